// Round 1
// baseline (260.428 us; speedup 1.0000x reference)
//
#include <hip/hip_runtime.h>

// CubicalModel: Xp = (I @ p).reshape(28,28); dgm1 = Xp[inds1[:,0], inds1[:,1]]
// Key insight: only 100 elements of each matvec are gathered, so compute only
// the 200 needed row-dot-products (40 MB read) instead of the full matvecs
// (313.6 MB read). Memory-bound: floor ~6.5 us at 6.3 TB/s.

#define P_DIM 50000
#define NV    (P_DIM / 4)      // 12500 float4 per row (P divisible by 4)
#define NGATH 100              // gathered elements per diagram
#define NOUT  200              // total outputs
#define SPLIT 4                // blocks per output row
#define CHUNK ((NV + SPLIT - 1) / SPLIT)  // 3125 float4 per block

__global__ __launch_bounds__(256) void gather_dot_partial(
    const float* __restrict__ p,
    const float* __restrict__ I,
    const float* __restrict__ J,
    const int*   __restrict__ inds1,
    const int*   __restrict__ inds2,
    float*       __restrict__ partials)
{
    const int b = blockIdx.x;       // 0 .. NOUT*SPLIT-1
    const int o = b / SPLIT;        // output index 0..199
    const int s = b % SPLIT;        // segment within the row

    const float* mat;
    const int*   ind;
    int k;
    if (o < NGATH) { mat = I; ind = inds1; k = o; }
    else           { mat = J; ind = inds2; k = o - NGATH; }

    const int r = ind[2 * k];
    const int c = ind[2 * k + 1];
    const size_t flat = (size_t)(r * 28 + c);   // row of the 784 x 50000 matrix

    const float4* __restrict__ row = (const float4*)(mat + flat * (size_t)P_DIM);
    const float4* __restrict__ p4  = (const float4*)p;

    const int start = s * CHUNK;
    const int end   = (start + CHUNK < NV) ? (start + CHUNK) : NV;

    float sum = 0.f;
    for (int i = start + (int)threadIdx.x; i < end; i += 256) {
        float4 a  = row[i];
        float4 pv = p4[i];
        sum += a.x * pv.x + a.y * pv.y + a.z * pv.z + a.w * pv.w;
    }

    // wave(64) shuffle reduction
    #pragma unroll
    for (int off = 32; off > 0; off >>= 1)
        sum += __shfl_down(sum, off, 64);

    __shared__ float smem[4];
    const int lane = threadIdx.x & 63;
    const int wave = threadIdx.x >> 6;
    if (lane == 0) smem[wave] = sum;
    __syncthreads();

    if (threadIdx.x == 0) {
        partials[o * SPLIT + s] = smem[0] + smem[1] + smem[2] + smem[3];
    }
}

__global__ void reduce_partials(const float* __restrict__ partials,
                                float* __restrict__ out)
{
    const int o = blockIdx.x * blockDim.x + threadIdx.x;
    if (o < NOUT) {
        float t = 0.f;
        #pragma unroll
        for (int s = 0; s < SPLIT; ++s) t += partials[o * SPLIT + s];
        out[o] = t;
    }
}

extern "C" void kernel_launch(void* const* d_in, const int* in_sizes, int n_in,
                              void* d_out, int out_size, void* d_ws, size_t ws_size,
                              hipStream_t stream) {
    const float* p     = (const float*)d_in[0];
    const float* I     = (const float*)d_in[1];
    const float* J     = (const float*)d_in[2];
    const int*   inds1 = (const int*)d_in[3];
    const int*   inds2 = (const int*)d_in[4];
    float* out      = (float*)d_out;
    float* partials = (float*)d_ws;   // NOUT*SPLIT floats = 3200 B

    gather_dot_partial<<<NOUT * SPLIT, 256, 0, stream>>>(p, I, J, inds1, inds2, partials);
    reduce_partials<<<1, 256, 0, stream>>>(partials, out);
}

// Round 2
// 260.333 us; speedup vs baseline: 1.0004x; 1.0004x over previous
//
#include <hip/hip_runtime.h>

// CubicalModel: Xp = (I @ p).reshape(28,28); dgm1 = Xp[inds1[:,0], inds1[:,1]]
// Only 100 elements of each matvec are gathered -> compute only the 200
// needed row-dot-products (~40 MB HBM read, ~176 unique rows) instead of the
// full matvecs (313.6 MB). Memory-bound floor ~6.5 us at 6.3 TB/s.
//
// R2: SPLIT 4->8 (1600 blocks = 6.25/CU for even XCD load balance), 2-way
// unrolled independent accumulators for ILP in the dot loop.

#define P_DIM 50000
#define NV    (P_DIM / 4)      // 12500 float4 per row
#define NGATH 100              // gathered elements per diagram
#define NOUT  200              // total outputs
#define SPLIT 8                // blocks per output row
#define CHUNK ((NV + SPLIT - 1) / SPLIT)  // 1563 float4 per block

__global__ __launch_bounds__(256) void gather_dot_partial(
    const float* __restrict__ p,
    const float* __restrict__ I,
    const float* __restrict__ J,
    const int*   __restrict__ inds1,
    const int*   __restrict__ inds2,
    float*       __restrict__ partials)
{
    const int b = blockIdx.x;       // 0 .. NOUT*SPLIT-1
    const int o = b / SPLIT;        // output index 0..199
    const int s = b % SPLIT;        // segment within the row

    const float* mat;
    const int*   ind;
    int k;
    if (o < NGATH) { mat = I; ind = inds1; k = o; }
    else           { mat = J; ind = inds2; k = o - NGATH; }

    const int r = ind[2 * k];
    const int c = ind[2 * k + 1];
    const size_t flat = (size_t)(r * 28 + c);   // row of the 784 x 50000 matrix

    const float4* __restrict__ row = (const float4*)(mat + flat * (size_t)P_DIM);
    const float4* __restrict__ p4  = (const float4*)p;

    const int start = s * CHUNK;
    const int end   = (start + CHUNK < NV) ? (start + CHUNK) : NV;

    float s0 = 0.f, s1 = 0.f;
    int i = start + (int)threadIdx.x;
    for (; i + 256 < end; i += 512) {
        float4 a0 = row[i];
        float4 p0 = p4[i];
        float4 a1 = row[i + 256];
        float4 p1 = p4[i + 256];
        s0 += a0.x * p0.x + a0.y * p0.y + a0.z * p0.z + a0.w * p0.w;
        s1 += a1.x * p1.x + a1.y * p1.y + a1.z * p1.z + a1.w * p1.w;
    }
    if (i < end) {
        float4 a0 = row[i];
        float4 p0 = p4[i];
        s0 += a0.x * p0.x + a0.y * p0.y + a0.z * p0.z + a0.w * p0.w;
    }
    float sum = s0 + s1;

    // wave(64) shuffle reduction
    #pragma unroll
    for (int off = 32; off > 0; off >>= 1)
        sum += __shfl_down(sum, off, 64);

    __shared__ float smem[4];
    const int lane = threadIdx.x & 63;
    const int wave = threadIdx.x >> 6;
    if (lane == 0) smem[wave] = sum;
    __syncthreads();

    if (threadIdx.x == 0) {
        partials[o * SPLIT + s] = smem[0] + smem[1] + smem[2] + smem[3];
    }
}

__global__ void reduce_partials(const float* __restrict__ partials,
                                float* __restrict__ out)
{
    const int o = blockIdx.x * blockDim.x + threadIdx.x;
    if (o < NOUT) {
        float t = 0.f;
        #pragma unroll
        for (int s = 0; s < SPLIT; ++s) t += partials[o * SPLIT + s];
        out[o] = t;
    }
}

extern "C" void kernel_launch(void* const* d_in, const int* in_sizes, int n_in,
                              void* d_out, int out_size, void* d_ws, size_t ws_size,
                              hipStream_t stream) {
    const float* p     = (const float*)d_in[0];
    const float* I     = (const float*)d_in[1];
    const float* J     = (const float*)d_in[2];
    const int*   inds1 = (const int*)d_in[3];
    const int*   inds2 = (const int*)d_in[4];
    float* out      = (float*)d_out;
    float* partials = (float*)d_ws;   // NOUT*SPLIT floats = 6400 B

    gather_dot_partial<<<NOUT * SPLIT, 256, 0, stream>>>(p, I, J, inds1, inds2, partials);
    reduce_partials<<<1, 256, 0, stream>>>(partials, out);
}